// Round 4
// baseline (330.537 us; speedup 1.0000x reference)
//
#include <hip/hip_runtime.h>
#include <math.h>

#define LL 1026          // sequence length S*S+2
#define EDim 512
#define MM 2052          // B0*LL
#define NC 8             // scan chunks (last chunk = 130 steps, others 128)
#define LC 128

struct Params {
  const float* cw[4];
  const float* cb[4];
  const float* xpw[4];
  const float* dtw[4];
  const float* dtb[4];
  const float* Al[4];
  const float* Dp[4];
};

// branch position l -> original position
__device__ __forceinline__ int sigma_map(int branch, int l) {
  if (branch & 1) l = LL - 1 - l;          // reverse
  if (branch & 2) {                        // S x S transpose of inner block
    if (l > 0 && l < LL - 1) {
      int p = l - 1;
      l = 1 + ((p & 31) << 5) + (p >> 5);
    }
  }
  return l;
}

__device__ __forceinline__ float silu_f(float v) { return v / (1.f + expf(-v)); }

template<int CTRL>
__device__ __forceinline__ float dpp_mov0(float x) {
  int r = __builtin_amdgcn_update_dpp(0, __float_as_int(x), CTRL, 0xF, 0xF, false);
  return __int_as_float(r);
}

// ---------------------------------------------------------------------------
// k1: xz = x @ in_w^T ; split into xa (cols 0..511) and sz = silu(za)
// M=2052, N=1024, K=256. BM=64 BN=64 BK=32, 256 thr, 4x4/thread.
// ---------------------------------------------------------------------------
__global__ __launch_bounds__(256) void k1_gemm_in(
    const float* __restrict__ x, const float* __restrict__ w,
    float* __restrict__ xa, float* __restrict__ sz) {
  __shared__ float As[32][65];
  __shared__ float Bs[32][65];
  const int t = threadIdx.x;
  const int tx = t & 15, ty = t >> 4;
  const int m0 = blockIdx.x * 64, n0 = blockIdx.y * 64;
  float acc[4][4] = {};
  for (int k0 = 0; k0 < 256; k0 += 32) {
    #pragma unroll
    for (int p = 0; p < 2; ++p) {
      int f = t + p * 256;            // 0..511
      int row = f >> 3, cf = f & 7;   // 64 rows x 8 float4
      int gr = m0 + row; gr = gr < MM ? gr : MM - 1;
      float4 v = *(const float4*)(x + (size_t)gr * 256 + k0 + cf * 4);
      As[cf*4+0][row] = v.x; As[cf*4+1][row] = v.y;
      As[cf*4+2][row] = v.z; As[cf*4+3][row] = v.w;
      int gn = n0 + row;
      float4 u = *(const float4*)(w + (size_t)gn * 256 + k0 + cf * 4);
      Bs[cf*4+0][row] = u.x; Bs[cf*4+1][row] = u.y;
      Bs[cf*4+2][row] = u.z; Bs[cf*4+3][row] = u.w;
    }
    __syncthreads();
    #pragma unroll
    for (int k = 0; k < 32; ++k) {
      float a0 = As[k][ty*4+0], a1 = As[k][ty*4+1], a2 = As[k][ty*4+2], a3 = As[k][ty*4+3];
      float b0 = Bs[k][tx*4+0], b1 = Bs[k][tx*4+1], b2 = Bs[k][tx*4+2], b3 = Bs[k][tx*4+3];
      acc[0][0]=fmaf(a0,b0,acc[0][0]); acc[0][1]=fmaf(a0,b1,acc[0][1]); acc[0][2]=fmaf(a0,b2,acc[0][2]); acc[0][3]=fmaf(a0,b3,acc[0][3]);
      acc[1][0]=fmaf(a1,b0,acc[1][0]); acc[1][1]=fmaf(a1,b1,acc[1][1]); acc[1][2]=fmaf(a1,b2,acc[1][2]); acc[1][3]=fmaf(a1,b3,acc[1][3]);
      acc[2][0]=fmaf(a2,b0,acc[2][0]); acc[2][1]=fmaf(a2,b1,acc[2][1]); acc[2][2]=fmaf(a2,b2,acc[2][2]); acc[2][3]=fmaf(a2,b3,acc[2][3]);
      acc[3][0]=fmaf(a3,b0,acc[3][0]); acc[3][1]=fmaf(a3,b1,acc[3][1]); acc[3][2]=fmaf(a3,b2,acc[3][2]); acc[3][3]=fmaf(a3,b3,acc[3][3]);
    }
    __syncthreads();
  }
  #pragma unroll
  for (int i = 0; i < 4; ++i) {
    int gm = m0 + ty*4 + i;
    if (gm < MM) {
      #pragma unroll
      for (int j = 0; j < 4; ++j) {
        int gn = n0 + tx*4 + j;
        float v = acc[i][j];
        if (gn < 512) xa[(size_t)gm*512 + gn] = v;
        else          sz[(size_t)gm*512 + gn - 512] = silu_f(v);
      }
    }
  }
}

// ---------------------------------------------------------------------------
// k2: per-branch conv(K=4, causal, depthwise)+silu -> xac ; dBC = xc @ xpw^T ;
//     delta = softplus(dBC[:,:16] @ dtw^T + dtb) ; store B,C.
// Projection reads weights DIRECTLY from global (16-lane broadcast, L1/L2
// resident) -- no xpw LDS staging, no mid-loop barriers.
// ---------------------------------------------------------------------------
__global__ __launch_bounds__(256) void k2_branch(
    Params P, const float* __restrict__ xa,
    float* __restrict__ xac, float* __restrict__ delta, float* __restrict__ bcg) {
  __shared__ float xcS[16][516];      // 516 % 32 = 4 -> 2-way (free) on b128 row reads
  __shared__ float dBCs[16][49];
  const int t = threadIdx.x;
  const int l0 = blockIdx.x * 16;
  const int b  = blockIdx.y;
  const int br = blockIdx.z;
  const int e0 = 2 * t;
  const float* cw = P.cw[br];
  const float w00 = cw[e0*4+0], w01 = cw[e0*4+1], w02 = cw[e0*4+2], w03 = cw[e0*4+3];
  const float w10 = cw[(e0+1)*4+0], w11 = cw[(e0+1)*4+1], w12 = cw[(e0+1)*4+2], w13 = cw[(e0+1)*4+3];
  const float cb0 = P.cb[br][e0], cb1 = P.cb[br][e0+1];
  const float* xab = xa + (size_t)b * LL * 512;
  const size_t obase = (size_t)(br*2 + b) * LL;

  float h0x=0,h0y=0,h1x=0,h1y=0,h2x=0,h2y=0,h3x=0,h3y=0;
  for (int i = -3; i < 16; ++i) {
    int l = l0 + i;
    float cx = 0.f, cy = 0.f;
    if (l >= 0 && l < LL) {
      int pos = sigma_map(br, l);
      float2 v = *(const float2*)(xab + (size_t)pos * 512 + e0);
      cx = v.x; cy = v.y;
    }
    h0x=h1x; h0y=h1y; h1x=h2x; h1y=h2y; h2x=h3x; h2y=h3y; h3x=cx; h3y=cy;
    if (i >= 0) {
      float o0 = fmaf(w00,h0x, fmaf(w01,h1x, fmaf(w02,h2x, fmaf(w03,h3x, cb0))));
      float o1 = fmaf(w10,h0y, fmaf(w11,h1y, fmaf(w12,h2y, fmaf(w13,h3y, cb1))));
      o0 = silu_f(o0); o1 = silu_f(o1);
      *(float2*)&xcS[i][e0] = make_float2(o0, o1);
      if (l < LL)
        *(float2*)(xac + (obase + l) * 512 + e0) = make_float2(o0, o1);
    }
  }
  __syncthreads();

  // projection: thread -> (row = t&15, r-cols r0, r0+16, r0+32), K = 512 in one pass
  const int rowi = t & 15;
  const int r0 = t >> 4;
  const float* xpw = P.xpw[br];
  const float4* xr4 = (const float4*)&xcS[rowi][0];
  const float4* wa = (const float4*)(xpw + (size_t)r0 * 512);
  const float4* wb = (const float4*)(xpw + (size_t)(r0 + 16) * 512);
  const float4* wc = (const float4*)(xpw + (size_t)(r0 + 32) * 512);
  float acc0 = 0.f, acc1 = 0.f, acc2 = 0.f;
  #pragma unroll 8
  for (int e4 = 0; e4 < 128; ++e4) {
    float4 xv = xr4[e4];
    float4 a = wa[e4], bb = wb[e4], c = wc[e4];
    acc0 = fmaf(xv.x,a.x, fmaf(xv.y,a.y, fmaf(xv.z,a.z, fmaf(xv.w,a.w, acc0))));
    acc1 = fmaf(xv.x,bb.x,fmaf(xv.y,bb.y,fmaf(xv.z,bb.z,fmaf(xv.w,bb.w,acc1))));
    acc2 = fmaf(xv.x,c.x, fmaf(xv.y,c.y, fmaf(xv.z,c.z, fmaf(xv.w,c.w, acc2))));
  }
  dBCs[rowi][r0]      = acc0;
  dBCs[rowi][r0 + 16] = acc1;
  dBCs[rowi][r0 + 32] = acc2;
  __syncthreads();

  // store B, C
  for (int idx = t; idx < 512; idx += 256) {
    int row = idx >> 5, c = idx & 31;
    int l = l0 + row;
    if (l < LL) bcg[(obase + l)*32 + c] = dBCs[row][16 + c];
  }

  // delta = softplus(dBC[:, :16] @ dtw^T + dtb)
  const float* dtw = P.dtw[br];
  float dw0[16], dw1[16];
  #pragma unroll
  for (int r = 0; r < 16; ++r) { dw0[r] = dtw[e0*16 + r]; dw1[r] = dtw[(e0+1)*16 + r]; }
  const float db0 = P.dtb[br][e0], db1 = P.dtb[br][e0+1];
  for (int row = 0; row < 16; ++row) {
    int l = l0 + row;
    if (l >= LL) break;
    float s0 = db0, s1 = db1;
    #pragma unroll
    for (int r = 0; r < 16; ++r) {
      float d = dBCs[row][r];
      s0 = fmaf(d, dw0[r], s0);
      s1 = fmaf(d, dw1[r], s1);
    }
    float sp0 = fmaxf(s0, 0.f) + log1pf(expf(-fabsf(s0)));
    float sp1 = fmaxf(s1, 0.f) + log1pf(expf(-fabsf(s1)));
    *(float2*)(delta + (obase + l)*512 + e0) = make_float2(sp0, sp1);
  }
}

// ---------------------------------------------------------------------------
// k3a: per-chunk scan summaries. For chunk c of chain (br,b,e,n):
//   P_c = prod da = exp(A_en * sum delta), Q_c = chunk-local scan (h_in = 0).
// grid (32 etiles, 2 b, 4 br * NC chunks), 256 thr.
// ---------------------------------------------------------------------------
__global__ __launch_bounds__(256) void k3a_chunk(
    Params P, const float* __restrict__ xac, const float* __restrict__ delta,
    const float* __restrict__ bcg, float* __restrict__ Pc, float* __restrict__ Qc) {
  __shared__ float dT[16][33], xT[16][33], bT[16][33];
  const int t = threadIdx.x;
  const int eL = t >> 4, n = t & 15;
  const int e0 = blockIdx.x * 16;
  const int b = blockIdx.y;
  const int br = blockIdx.z / NC, c = blockIdx.z % NC;
  const size_t sbase = (size_t)(br*2 + b) * LL;
  const float* dl = delta + sbase * 512;
  const float* xc = xac + sbase * 512;
  const float* bc = bcg + sbase * 32;
  const float A_en = -expf(P.Al[br][(e0 + eL)*16 + n]);
  const int l0 = c * LC;
  const int lend = (c == NC-1) ? LL : (l0 + LC);
  float h = 0.f, dsum = 0.f;

  for (int c0 = l0; c0 < lend; c0 += 32) {
    #pragma unroll
    for (int p = 0; p < 2; ++p) {
      int idx = t + p*256;
      int s = idx >> 4, ee = idx & 15;
      int l = c0 + s;
      float dv = 0.f, xv = 0.f, bv = 0.f;
      if (l < lend) {
        dv = dl[(size_t)l*512 + e0 + ee];
        xv = xc[(size_t)l*512 + e0 + ee];
        bv = bc[l*32 + ee];
      }
      dT[ee][s] = dv; xT[ee][s] = xv; bT[ee][s] = bv;
    }
    __syncthreads();
    float da[32], dbx[32];
    #pragma unroll
    for (int s = 0; s < 32; ++s) {
      float d = dT[eL][s];
      da[s]  = __expf(d * A_en);           // d=0 pad -> 1 (identity)
      dbx[s] = d * xT[eL][s] * bT[n][s];   // pad -> 0
      dsum += d;
    }
    #pragma unroll
    for (int s = 0; s < 32; ++s) h = fmaf(da[s], h, dbx[s]);
    __syncthreads();
  }
  size_t oi = ((((size_t)(br*2 + b)*NC + c)*32 + blockIdx.x)*256 + t);
  Pc[oi] = __expf(dsum * A_en);
  Qc[oi] = h;
}

// ---------------------------------------------------------------------------
// k3b: chunk-parallel output scan. h_in built from preceding (P,Q) pairs
// (<=7 fmas), then the local scan produces y and the gated write.
// ---------------------------------------------------------------------------
__global__ __launch_bounds__(256) void k3b_scan(
    Params P, const float* __restrict__ xac, const float* __restrict__ delta,
    const float* __restrict__ bcg, const float* __restrict__ sz,
    const float* __restrict__ Pc, const float* __restrict__ Qc,
    float* __restrict__ g) {
  __shared__ float dT[16][33], xT[16][33], bT[16][33], cT[16][33];
  __shared__ float ybuf[32][17];
  const int t = threadIdx.x;
  const int eL = t >> 4, n = t & 15;
  const int e0 = blockIdx.x * 16;
  const int b = blockIdx.y;
  const int br = blockIdx.z / NC, c = blockIdx.z % NC;
  const size_t sbase = (size_t)(br*2 + b) * LL;
  const float* dl = delta + sbase * 512;
  const float* xc = xac + sbase * 512;
  const float* bc = bcg + sbase * 32;
  const float A_en = -expf(P.Al[br][(e0 + eL)*16 + n]);
  const float Dval = P.Dp[br][e0 + (t & 15)];
  const float* szb = sz + (size_t)b * LL * 512;
  float* gb = g + (size_t)br * MM * 512 + (size_t)b * LL * 512;

  // h_in for this chunk: h[c] = P[c-1]*h[c-1] + Q[c-1], h[0]=0
  float h = 0.f;
  for (int cc = 0; cc < c; ++cc) {
    size_t ii = ((((size_t)(br*2 + b)*NC + cc)*32 + blockIdx.x)*256 + t);
    h = fmaf(Pc[ii], h, Qc[ii]);
  }

  const int l0c = c * LC;
  const int lend = (c == NC-1) ? LL : (l0c + LC);
  for (int c0 = l0c; c0 < lend; c0 += 32) {
    #pragma unroll
    for (int p = 0; p < 2; ++p) {
      int idx = t + p*256;
      int s = idx >> 4, ee = idx & 15;
      int l = c0 + s;
      float dv = 0.f, xv = 0.f, bv = 0.f, cv = 0.f;
      if (l < lend) {
        dv = dl[(size_t)l*512 + e0 + ee];
        xv = xc[(size_t)l*512 + e0 + ee];
        bv = bc[l*32 + ee];
        cv = bc[l*32 + 16 + ee];
      }
      dT[ee][s] = dv; xT[ee][s] = xv; bT[ee][s] = bv; cT[ee][s] = cv;
    }
    __syncthreads();

    float da[32], dbx[32], ccv[32];
    #pragma unroll
    for (int s = 0; s < 32; ++s) {
      float d  = dT[eL][s];
      float xv = xT[eL][s];
      da[s]  = __expf(d * A_en);
      dbx[s] = d * xv * bT[n][s];
      ccv[s] = cT[n][s];
    }
    #pragma unroll
    for (int s = 0; s < 32; ++s) {
      h = fmaf(da[s], h, dbx[s]);
      float r = h * ccv[s];
      r += dpp_mov0<0xB1>(r);    // quad_perm xor1
      r += dpp_mov0<0x4E>(r);    // quad_perm xor2
      r += dpp_mov0<0x114>(r);   // row_shr:4
      r += dpp_mov0<0x118>(r);   // row_shr:8 -> lane 15 of each 16 holds sum
      if (n == 15) ybuf[s][eL] = r;
    }
    __syncthreads();

    #pragma unroll
    for (int p = 0; p < 2; ++p) {
      int idx = t + p*256;
      int s = idx >> 4, ee = idx & 15;
      int l = c0 + s;
      if (l < lend) {
        float yv = fmaf(Dval, xT[ee][s], ybuf[s][ee]);
        int pos = sigma_map(br, l);
        float szv = szb[(size_t)pos * 512 + e0 + ee];
        gb[(size_t)pos * 512 + e0 + ee] = yv * szv;
      }
    }
    __syncthreads();
  }
}

// ---------------------------------------------------------------------------
// k4: out = (0.25 * (g0+g1+g2+g3)) @ out_w^T.  M=2052 N=256 K=512.
// ---------------------------------------------------------------------------
__global__ __launch_bounds__(256) void k4_gemm_out(
    const float* __restrict__ g, const float* __restrict__ w, float* __restrict__ out) {
  __shared__ float As[32][65];
  __shared__ float Bs[32][33];
  const int t = threadIdx.x;
  const int tx = t & 15, ty = t >> 4;
  const int m0 = blockIdx.x * 64, n0 = blockIdx.y * 32;
  const float* g1 = g + (size_t)MM*512;
  const float* g2 = g + (size_t)2*MM*512;
  const float* g3 = g + (size_t)3*MM*512;
  float acc[4][2] = {};
  for (int k0 = 0; k0 < 512; k0 += 32) {
    #pragma unroll
    for (int p = 0; p < 8; ++p) {
      int idx = t + p*256;
      int row = idx >> 5, kk = idx & 31;
      int gm = m0 + row; gm = gm < MM ? gm : MM - 1;
      size_t ga = (size_t)gm*512 + k0 + kk;
      As[kk][row] = 0.25f * (g[ga] + g1[ga] + g2[ga] + g3[ga]);
    }
    #pragma unroll
    for (int p = 0; p < 4; ++p) {
      int idx = t + p*256;
      int row = idx >> 5, kk = idx & 31;
      Bs[kk][row] = w[(size_t)(n0 + row)*512 + k0 + kk];
    }
    __syncthreads();
    #pragma unroll
    for (int k = 0; k < 32; ++k) {
      float a0 = As[k][ty*4+0], a1 = As[k][ty*4+1], a2 = As[k][ty*4+2], a3 = As[k][ty*4+3];
      float b0 = Bs[k][tx*2+0], b1 = Bs[k][tx*2+1];
      acc[0][0]=fmaf(a0,b0,acc[0][0]); acc[0][1]=fmaf(a0,b1,acc[0][1]);
      acc[1][0]=fmaf(a1,b0,acc[1][0]); acc[1][1]=fmaf(a1,b1,acc[1][1]);
      acc[2][0]=fmaf(a2,b0,acc[2][0]); acc[2][1]=fmaf(a2,b1,acc[2][1]);
      acc[3][0]=fmaf(a3,b0,acc[3][0]); acc[3][1]=fmaf(a3,b1,acc[3][1]);
    }
    __syncthreads();
  }
  #pragma unroll
  for (int i = 0; i < 4; ++i) {
    int gm = m0 + ty*4 + i;
    if (gm < MM) {
      out[(size_t)gm*256 + n0 + tx*2 + 0] = acc[i][0];
      out[(size_t)gm*256 + n0 + tx*2 + 1] = acc[i][1];
    }
  }
}

// ---------------------------------------------------------------------------
extern "C" void kernel_launch(void* const* d_in, const int* in_sizes, int n_in,
                              void* d_out, int out_size, void* d_ws, size_t ws_size,
                              hipStream_t stream) {
  const float* x    = (const float*)d_in[0];
  const float* in_w = (const float*)d_in[1];
  const float* out_w= (const float*)d_in[2];
  Params prm;
  for (int s = 0; s < 4; ++s) {
    prm.cw[s]  = (const float*)d_in[3 + s*7 + 0];
    prm.cb[s]  = (const float*)d_in[3 + s*7 + 1];
    prm.xpw[s] = (const float*)d_in[3 + s*7 + 2];
    prm.dtw[s] = (const float*)d_in[3 + s*7 + 3];
    prm.dtb[s] = (const float*)d_in[3 + s*7 + 4];
    prm.Al[s]  = (const float*)d_in[3 + s*7 + 5];
    prm.Dp[s]  = (const float*)d_in[3 + s*7 + 6];
  }
  float* ws = (float*)d_ws;
  const size_t SZ1 = (size_t)MM * 512;        // 1,050,624 floats
  float* xa   = ws;                            // [MM][512]   (reused as Pc/Qc after k2)
  float* szp  = ws + SZ1;                      // [MM][512]
  float* xac  = ws + 2*SZ1;                    // [4][MM][512] branch-ordered
  float* dlt  = ws + 6*SZ1;                    // [4][MM][512]
  float* bc   = ws + 10*SZ1;                   // [4][MM][32]
  float* gbuf = ws + 10*SZ1 + (size_t)4*MM*32; // [4][MM][512] original-ordered
  // Pc/Qc overlay xa (dead after k2): 8*NC*32*256 = 524288 floats each
  float* Pc = xa;
  float* Qc = xa + (size_t)8*NC*32*256;

  k1_gemm_in<<<dim3(33, 16), 256, 0, stream>>>(x, in_w, xa, szp);
  k2_branch <<<dim3(65, 2, 4), 256, 0, stream>>>(prm, xa, xac, dlt, bc);
  k3a_chunk <<<dim3(32, 2, 4*NC), 256, 0, stream>>>(prm, xac, dlt, bc, Pc, Qc);
  k3b_scan  <<<dim3(32, 2, 4*NC), 256, 0, stream>>>(prm, xac, dlt, bc, szp, Pc, Qc, gbuf);
  k4_gemm_out<<<dim3(33, 8), 256, 0, stream>>>(gbuf, out_w, (float*)d_out);
}

// Round 6
// 326.429 us; speedup vs baseline: 1.0126x; 1.0126x over previous
//
#include <hip/hip_runtime.h>
#include <math.h>

#define LL 1026          // sequence length S*S+2
#define EDim 512
#define MM 2052          // B0*LL
#define NC 8             // scan chunks (last chunk = 130 steps, others 128)
#define LC 128

struct Params {
  const float* cw[4];
  const float* cb[4];
  const float* xpw[4];
  const float* dtw[4];
  const float* dtb[4];
  const float* Al[4];
  const float* Dp[4];
};

// branch position l -> original position
__device__ __forceinline__ int sigma_map(int branch, int l) {
  if (branch & 1) l = LL - 1 - l;          // reverse
  if (branch & 2) {                        // S x S transpose of inner block
    if (l > 0 && l < LL - 1) {
      int p = l - 1;
      l = 1 + ((p & 31) << 5) + (p >> 5);
    }
  }
  return l;
}

__device__ __forceinline__ float silu_f(float v) { return v / (1.f + expf(-v)); }

template<int CTRL>
__device__ __forceinline__ float dpp_mov0(float x) {
  int r = __builtin_amdgcn_update_dpp(0, __float_as_int(x), CTRL, 0xF, 0xF, false);
  return __int_as_float(r);
}

// ---------------------------------------------------------------------------
// k1: xz = x @ in_w^T ; split into xa (cols 0..511) and sz = silu(za)
// M=2052, N=1024, K=256. BM=64 BN=64 BK=32, 256 thr, 4x4/thread.
// LDS rows padded to 68 -> 16B-aligned float4 fragment reads.
// ---------------------------------------------------------------------------
__global__ __launch_bounds__(256) void k1_gemm_in(
    const float* __restrict__ x, const float* __restrict__ w,
    float* __restrict__ xa, float* __restrict__ sz) {
  __shared__ float As[32][68];
  __shared__ float Bs[32][68];
  const int t = threadIdx.x;
  const int tx = t & 15, ty = t >> 4;
  const int m0 = blockIdx.x * 64, n0 = blockIdx.y * 64;
  float acc[4][4] = {};
  for (int k0 = 0; k0 < 256; k0 += 32) {
    #pragma unroll
    for (int p = 0; p < 2; ++p) {
      int f = t + p * 256;            // 0..511
      int row = f >> 3, cf = f & 7;   // 64 rows x 8 float4
      int gr = m0 + row; gr = gr < MM ? gr : MM - 1;
      float4 v = *(const float4*)(x + (size_t)gr * 256 + k0 + cf * 4);
      As[cf*4+0][row] = v.x; As[cf*4+1][row] = v.y;
      As[cf*4+2][row] = v.z; As[cf*4+3][row] = v.w;
      int gn = n0 + row;
      float4 u = *(const float4*)(w + (size_t)gn * 256 + k0 + cf * 4);
      Bs[cf*4+0][row] = u.x; Bs[cf*4+1][row] = u.y;
      Bs[cf*4+2][row] = u.z; Bs[cf*4+3][row] = u.w;
    }
    __syncthreads();
    #pragma unroll
    for (int k = 0; k < 32; ++k) {
      float4 av = *(const float4*)&As[k][ty*4];
      float4 bv = *(const float4*)&Bs[k][tx*4];
      float a0 = av.x, a1 = av.y, a2 = av.z, a3 = av.w;
      float b0 = bv.x, b1 = bv.y, b2 = bv.z, b3 = bv.w;
      acc[0][0]=fmaf(a0,b0,acc[0][0]); acc[0][1]=fmaf(a0,b1,acc[0][1]); acc[0][2]=fmaf(a0,b2,acc[0][2]); acc[0][3]=fmaf(a0,b3,acc[0][3]);
      acc[1][0]=fmaf(a1,b0,acc[1][0]); acc[1][1]=fmaf(a1,b1,acc[1][1]); acc[1][2]=fmaf(a1,b2,acc[1][2]); acc[1][3]=fmaf(a1,b3,acc[1][3]);
      acc[2][0]=fmaf(a2,b0,acc[2][0]); acc[2][1]=fmaf(a2,b1,acc[2][1]); acc[2][2]=fmaf(a2,b2,acc[2][2]); acc[2][3]=fmaf(a2,b3,acc[2][3]);
      acc[3][0]=fmaf(a3,b0,acc[3][0]); acc[3][1]=fmaf(a3,b1,acc[3][1]); acc[3][2]=fmaf(a3,b2,acc[3][2]); acc[3][3]=fmaf(a3,b3,acc[3][3]);
    }
    __syncthreads();
  }
  #pragma unroll
  for (int i = 0; i < 4; ++i) {
    int gm = m0 + ty*4 + i;
    if (gm < MM) {
      #pragma unroll
      for (int j = 0; j < 4; ++j) {
        int gn = n0 + tx*4 + j;
        float v = acc[i][j];
        if (gn < 512) xa[(size_t)gm*512 + gn] = v;
        else          sz[(size_t)gm*512 + gn - 512] = silu_f(v);
      }
    }
  }
}

// ---------------------------------------------------------------------------
// k2: per-branch conv(K=4)+silu -> xac ; dBC = xc @ xpw^T ; delta; store B,C.
// 8-row tiles (grid 129x2x4 = 1032 blocks, 4/CU) for latency hiding.
// Projection: balanced (row, halfK, r) split-K x2 mapping, weights direct
// from global (16-lane-shared addresses, L2 resident).
// ---------------------------------------------------------------------------
__global__ __launch_bounds__(256) void k2_branch(
    Params P, const float* __restrict__ xa,
    float* __restrict__ xac, float* __restrict__ delta, float* __restrict__ bcg) {
  __shared__ float xcS[8][516];
  __shared__ float dBCs[8][2][52];   // [row][halfK][r<48]
  const int t = threadIdx.x;
  const int l0 = blockIdx.x * 8;
  const int b  = blockIdx.y;
  const int br = blockIdx.z;
  const int e0 = 2 * t;
  const float* cw = P.cw[br];
  const float w00 = cw[e0*4+0], w01 = cw[e0*4+1], w02 = cw[e0*4+2], w03 = cw[e0*4+3];
  const float w10 = cw[(e0+1)*4+0], w11 = cw[(e0+1)*4+1], w12 = cw[(e0+1)*4+2], w13 = cw[(e0+1)*4+3];
  const float cb0 = P.cb[br][e0], cb1 = P.cb[br][e0+1];
  const float* xab = xa + (size_t)b * LL * 512;
  const size_t obase = (size_t)(br*2 + b) * LL;

  float h0x=0,h0y=0,h1x=0,h1y=0,h2x=0,h2y=0,h3x=0,h3y=0;
  for (int i = -3; i < 8; ++i) {
    int l = l0 + i;
    float cx = 0.f, cy = 0.f;
    if (l >= 0 && l < LL) {
      int pos = sigma_map(br, l);
      float2 v = *(const float2*)(xab + (size_t)pos * 512 + e0);
      cx = v.x; cy = v.y;
    }
    h0x=h1x; h0y=h1y; h1x=h2x; h1y=h2y; h2x=h3x; h2y=h3y; h3x=cx; h3y=cy;
    if (i >= 0) {
      float o0 = fmaf(w00,h0x, fmaf(w01,h1x, fmaf(w02,h2x, fmaf(w03,h3x, cb0))));
      float o1 = fmaf(w10,h0y, fmaf(w11,h1y, fmaf(w12,h2y, fmaf(w13,h3y, cb1))));
      o0 = silu_f(o0); o1 = silu_f(o1);
      *(float2*)&xcS[i][e0] = make_float2(o0, o1);
      if (l < LL)
        *(float2*)(xac + (obase + l) * 512 + e0) = make_float2(o0, o1);
    }
  }
  __syncthreads();

  // projection, split-K x2: thread -> (prow, phalf) from t&15, r set {tg,tg+16,tg+32}
  const int combo = t & 15;
  const int prow = combo >> 1, phalf = combo & 1;
  const int tg = t >> 4;              // 0..15
  const float* xpw = P.xpw[br];
  const float4* xr4 = (const float4*)&xcS[prow][phalf*256];
  const float4* wa = (const float4*)(xpw + (size_t)tg*512        + phalf*256);
  const float4* wb = (const float4*)(xpw + (size_t)(tg+16)*512   + phalf*256);
  const float4* wc = (const float4*)(xpw + (size_t)(tg+32)*512   + phalf*256);
  float acc0 = 0.f, acc1 = 0.f, acc2 = 0.f;
  #pragma unroll 8
  for (int e4 = 0; e4 < 64; ++e4) {
    float4 xv = xr4[e4];
    float4 a = wa[e4], bb = wb[e4], c = wc[e4];
    acc0 = fmaf(xv.x,a.x, fmaf(xv.y,a.y, fmaf(xv.z,a.z, fmaf(xv.w,a.w, acc0))));
    acc1 = fmaf(xv.x,bb.x,fmaf(xv.y,bb.y,fmaf(xv.z,bb.z,fmaf(xv.w,bb.w,acc1))));
    acc2 = fmaf(xv.x,c.x, fmaf(xv.y,c.y, fmaf(xv.z,c.z, fmaf(xv.w,c.w, acc2))));
  }
  dBCs[prow][phalf][tg]      = acc0;
  dBCs[prow][phalf][tg + 16] = acc1;
  dBCs[prow][phalf][tg + 32] = acc2;
  __syncthreads();

  // store B, C (8 rows x 32 cols = 256 -> one per thread)
  {
    int row = t >> 5, c = t & 31;
    int l = l0 + row;
    if (l < LL)
      bcg[(obase + l)*32 + c] = dBCs[row][0][16 + c] + dBCs[row][1][16 + c];
  }

  // delta = softplus(dBC[:, :16] @ dtw^T + dtb)
  const float* dtw = P.dtw[br];
  float dw0[16], dw1[16];
  #pragma unroll
  for (int r = 0; r < 16; ++r) { dw0[r] = dtw[e0*16 + r]; dw1[r] = dtw[(e0+1)*16 + r]; }
  const float db0 = P.dtb[br][e0], db1 = P.dtb[br][e0+1];
  for (int row = 0; row < 8; ++row) {
    int l = l0 + row;
    if (l >= LL) break;
    float s0 = db0, s1 = db1;
    #pragma unroll
    for (int r = 0; r < 16; ++r) {
      float d = dBCs[row][0][r] + dBCs[row][1][r];
      s0 = fmaf(d, dw0[r], s0);
      s1 = fmaf(d, dw1[r], s1);
    }
    float sp0 = fmaxf(s0, 0.f) + log1pf(expf(-fabsf(s0)));
    float sp1 = fmaxf(s1, 0.f) + log1pf(expf(-fabsf(s1)));
    *(float2*)(delta + (obase + l)*512 + e0) = make_float2(sp0, sp1);
  }
}

// ---------------------------------------------------------------------------
// k3a: per-chunk scan summaries. For chunk c of chain (br,b,e,n):
//   P_c = prod da = exp(A_en * sum delta), Q_c = chunk-local scan (h_in = 0).
// ---------------------------------------------------------------------------
__global__ __launch_bounds__(256) void k3a_chunk(
    Params P, const float* __restrict__ xac, const float* __restrict__ delta,
    const float* __restrict__ bcg, float* __restrict__ Pc, float* __restrict__ Qc) {
  __shared__ float dT[16][33], xT[16][33], bT[16][33];
  const int t = threadIdx.x;
  const int eL = t >> 4, n = t & 15;
  const int e0 = blockIdx.x * 16;
  const int b = blockIdx.y;
  const int br = blockIdx.z / NC, c = blockIdx.z % NC;
  const size_t sbase = (size_t)(br*2 + b) * LL;
  const float* dl = delta + sbase * 512;
  const float* xc = xac + sbase * 512;
  const float* bc = bcg + sbase * 32;
  const float A_en = -expf(P.Al[br][(e0 + eL)*16 + n]);
  const int l0 = c * LC;
  const int lend = (c == NC-1) ? LL : (l0 + LC);
  float h = 0.f, dsum = 0.f;

  for (int c0 = l0; c0 < lend; c0 += 32) {
    #pragma unroll
    for (int p = 0; p < 2; ++p) {
      int idx = t + p*256;
      int s = idx >> 4, ee = idx & 15;
      int l = c0 + s;
      float dv = 0.f, xv = 0.f, bv = 0.f;
      if (l < lend) {
        dv = dl[(size_t)l*512 + e0 + ee];
        xv = xc[(size_t)l*512 + e0 + ee];
        bv = bc[l*32 + ee];
      }
      dT[ee][s] = dv; xT[ee][s] = xv; bT[ee][s] = bv;
    }
    __syncthreads();
    float da[32], dbx[32];
    #pragma unroll
    for (int s = 0; s < 32; ++s) {
      float d = dT[eL][s];
      da[s]  = __expf(d * A_en);           // d=0 pad -> 1 (identity)
      dbx[s] = d * xT[eL][s] * bT[n][s];   // pad -> 0
      dsum += d;
    }
    #pragma unroll
    for (int s = 0; s < 32; ++s) h = fmaf(da[s], h, dbx[s]);
    __syncthreads();
  }
  size_t oi = ((((size_t)(br*2 + b)*NC + c)*32 + blockIdx.x)*256 + t);
  Pc[oi] = __expf(dsum * A_en);
  Qc[oi] = h;
}

// ---------------------------------------------------------------------------
// k3b: chunk-parallel output scan. h_in built from preceding (P,Q) pairs
// (<=7 fmas), then the local scan produces y and the gated write.
// ---------------------------------------------------------------------------
__global__ __launch_bounds__(256) void k3b_scan(
    Params P, const float* __restrict__ xac, const float* __restrict__ delta,
    const float* __restrict__ bcg, const float* __restrict__ sz,
    const float* __restrict__ Pc, const float* __restrict__ Qc,
    float* __restrict__ g) {
  __shared__ float dT[16][33], xT[16][33], bT[16][33], cT[16][33];
  __shared__ float ybuf[32][17];
  const int t = threadIdx.x;
  const int eL = t >> 4, n = t & 15;
  const int e0 = blockIdx.x * 16;
  const int b = blockIdx.y;
  const int br = blockIdx.z / NC, c = blockIdx.z % NC;
  const size_t sbase = (size_t)(br*2 + b) * LL;
  const float* dl = delta + sbase * 512;
  const float* xc = xac + sbase * 512;
  const float* bc = bcg + sbase * 32;
  const float A_en = -expf(P.Al[br][(e0 + eL)*16 + n]);
  const float Dval = P.Dp[br][e0 + (t & 15)];
  const float* szb = sz + (size_t)b * LL * 512;
  float* gb = g + (size_t)br * MM * 512 + (size_t)b * LL * 512;

  // h_in for this chunk: h[c] = P[c-1]*h[c-1] + Q[c-1], h[0]=0
  float h = 0.f;
  for (int cc = 0; cc < c; ++cc) {
    size_t ii = ((((size_t)(br*2 + b)*NC + cc)*32 + blockIdx.x)*256 + t);
    h = fmaf(Pc[ii], h, Qc[ii]);
  }

  const int l0c = c * LC;
  const int lend = (c == NC-1) ? LL : (l0c + LC);
  for (int c0 = l0c; c0 < lend; c0 += 32) {
    #pragma unroll
    for (int p = 0; p < 2; ++p) {
      int idx = t + p*256;
      int s = idx >> 4, ee = idx & 15;
      int l = c0 + s;
      float dv = 0.f, xv = 0.f, bv = 0.f, cv = 0.f;
      if (l < lend) {
        dv = dl[(size_t)l*512 + e0 + ee];
        xv = xc[(size_t)l*512 + e0 + ee];
        bv = bc[l*32 + ee];
        cv = bc[l*32 + 16 + ee];
      }
      dT[ee][s] = dv; xT[ee][s] = xv; bT[ee][s] = bv; cT[ee][s] = cv;
    }
    __syncthreads();

    float da[32], dbx[32], ccv[32];
    #pragma unroll
    for (int s = 0; s < 32; ++s) {
      float d  = dT[eL][s];
      float xv = xT[eL][s];
      da[s]  = __expf(d * A_en);
      dbx[s] = d * xv * bT[n][s];
      ccv[s] = cT[n][s];
    }
    #pragma unroll
    for (int s = 0; s < 32; ++s) {
      h = fmaf(da[s], h, dbx[s]);
      float r = h * ccv[s];
      r += dpp_mov0<0xB1>(r);    // quad_perm xor1
      r += dpp_mov0<0x4E>(r);    // quad_perm xor2
      r += dpp_mov0<0x114>(r);   // row_shr:4
      r += dpp_mov0<0x118>(r);   // row_shr:8 -> lane 15 of each 16 holds sum
      if (n == 15) ybuf[s][eL] = r;
    }
    __syncthreads();

    #pragma unroll
    for (int p = 0; p < 2; ++p) {
      int idx = t + p*256;
      int s = idx >> 4, ee = idx & 15;
      int l = c0 + s;
      if (l < lend) {
        float yv = fmaf(Dval, xT[ee][s], ybuf[s][ee]);
        int pos = sigma_map(br, l);
        float szv = szb[(size_t)pos * 512 + e0 + ee];
        gb[(size_t)pos * 512 + e0 + ee] = yv * szv;
      }
    }
    __syncthreads();
  }
}

// ---------------------------------------------------------------------------
// k4: out = (0.25 * (g0+g1+g2+g3)) @ out_w^T.  M=2052 N=256 K=512.
// BM=32 BN=32 BK=32 -> grid (65,8)=520 blocks (2/CU). k-major [32][38] tiles,
// float2 fragment reads, 2x2 acc/thread.
// ---------------------------------------------------------------------------
__global__ __launch_bounds__(256) void k4_gemm_out(
    const float* __restrict__ g, const float* __restrict__ w, float* __restrict__ out) {
  __shared__ float As[32][38];
  __shared__ float Bs[32][38];
  const int t = threadIdx.x;
  const int tx = t & 15, ty = t >> 4;
  const int m0 = blockIdx.x * 32, n0 = blockIdx.y * 32;
  const float* g1 = g + (size_t)MM*512;
  const float* g2 = g + (size_t)2*MM*512;
  const float* g3 = g + (size_t)3*MM*512;
  float acc[2][2] = {};
  for (int k0 = 0; k0 < 512; k0 += 32) {
    #pragma unroll
    for (int p = 0; p < 4; ++p) {
      int idx = t + p*256;
      int row = idx >> 5, kk = idx & 31;
      int gm = m0 + row; gm = gm < MM ? gm : MM - 1;
      size_t ga = (size_t)gm*512 + k0 + kk;
      As[kk][row] = 0.25f * (g[ga] + g1[ga] + g2[ga] + g3[ga]);
    }
    #pragma unroll
    for (int p = 0; p < 4; ++p) {
      int idx = t + p*256;
      int row = idx >> 5, kk = idx & 31;
      Bs[kk][row] = w[(size_t)(n0 + row)*512 + k0 + kk];
    }
    __syncthreads();
    #pragma unroll
    for (int k = 0; k < 32; ++k) {
      float2 av = *(const float2*)&As[k][ty*2];
      float2 bv = *(const float2*)&Bs[k][tx*2];
      acc[0][0]=fmaf(av.x,bv.x,acc[0][0]); acc[0][1]=fmaf(av.x,bv.y,acc[0][1]);
      acc[1][0]=fmaf(av.y,bv.x,acc[1][0]); acc[1][1]=fmaf(av.y,bv.y,acc[1][1]);
    }
    __syncthreads();
  }
  #pragma unroll
  for (int i = 0; i < 2; ++i) {
    int gm = m0 + ty*2 + i;
    if (gm < MM) {
      #pragma unroll
      for (int j = 0; j < 2; ++j)
        out[(size_t)gm*256 + n0 + tx*2 + j] = acc[i][j];
    }
  }
}

// ---------------------------------------------------------------------------
extern "C" void kernel_launch(void* const* d_in, const int* in_sizes, int n_in,
                              void* d_out, int out_size, void* d_ws, size_t ws_size,
                              hipStream_t stream) {
  const float* x    = (const float*)d_in[0];
  const float* in_w = (const float*)d_in[1];
  const float* out_w= (const float*)d_in[2];
  Params prm;
  for (int s = 0; s < 4; ++s) {
    prm.cw[s]  = (const float*)d_in[3 + s*7 + 0];
    prm.cb[s]  = (const float*)d_in[3 + s*7 + 1];
    prm.xpw[s] = (const float*)d_in[3 + s*7 + 2];
    prm.dtw[s] = (const float*)d_in[3 + s*7 + 3];
    prm.dtb[s] = (const float*)d_in[3 + s*7 + 4];
    prm.Al[s]  = (const float*)d_in[3 + s*7 + 5];
    prm.Dp[s]  = (const float*)d_in[3 + s*7 + 6];
  }
  float* ws = (float*)d_ws;
  const size_t SZ1 = (size_t)MM * 512;        // 1,050,624 floats
  float* xa   = ws;                            // [MM][512]   (reused as Pc/Qc after k2)
  float* szp  = ws + SZ1;                      // [MM][512]
  float* xac  = ws + 2*SZ1;                    // [4][MM][512] branch-ordered
  float* dlt  = ws + 6*SZ1;                    // [4][MM][512]
  float* bc   = ws + 10*SZ1;                   // [4][MM][32]
  float* gbuf = ws + 10*SZ1 + (size_t)4*MM*32; // [4][MM][512] original-ordered
  // Pc/Qc overlay xa (dead after k2): 8*NC*32*256 = 524288 floats each
  float* Pc = xa;
  float* Qc = xa + (size_t)8*NC*32*256;

  k1_gemm_in<<<dim3(33, 16), 256, 0, stream>>>(x, in_w, xa, szp);
  k2_branch <<<dim3(129, 2, 4), 256, 0, stream>>>(prm, xa, xac, dlt, bc);
  k3a_chunk <<<dim3(32, 2, 4*NC), 256, 0, stream>>>(prm, xac, dlt, bc, Pc, Qc);
  k3b_scan  <<<dim3(32, 2, 4*NC), 256, 0, stream>>>(prm, xac, dlt, bc, szp, Pc, Qc, gbuf);
  k4_gemm_out<<<dim3(65, 8), 256, 0, stream>>>(gbuf, out_w, (float*)d_out);
}

// Round 7
// 300.432 us; speedup vs baseline: 1.1002x; 1.0865x over previous
//
#include <hip/hip_runtime.h>
#include <math.h>

#define LL 1026          // sequence length S*S+2
#define EDim 512
#define MM 2052          // B0*LL
#define NC 8             // scan chunks (last chunk = 130 steps, others 128)
#define LC 128

struct Params {
  const float* cw[4];
  const float* cb[4];
  const float* xpw[4];
  const float* dtw[4];
  const float* dtb[4];
  const float* Al[4];
  const float* Dp[4];
};

// branch position l -> original position
__device__ __forceinline__ int sigma_map(int branch, int l) {
  if (branch & 1) l = LL - 1 - l;          // reverse
  if (branch & 2) {                        // S x S transpose of inner block
    if (l > 0 && l < LL - 1) {
      int p = l - 1;
      l = 1 + ((p & 31) << 5) + (p >> 5);
    }
  }
  return l;
}

// fast silu: v * rcp(1 + exp2(-v*log2e))  (~1ulp rcp, ~1e-7 rel)
__device__ __forceinline__ float silu_f(float v) {
  return v * __builtin_amdgcn_rcpf(1.f + __expf(-v));
}
// fast softplus: max(s,0) + log(1 + exp(-|s|))
__device__ __forceinline__ float softplus_f(float s) {
  return fmaxf(s, 0.f) + __logf(1.f + __expf(-fabsf(s)));
}

template<int CTRL>
__device__ __forceinline__ float dpp_mov0(float x) {
  int r = __builtin_amdgcn_update_dpp(0, __float_as_int(x), CTRL, 0xF, 0xF, false);
  return __int_as_float(r);
}

// ---------------------------------------------------------------------------
// k1: xz = x @ in_w^T ; split into xa (cols 0..511) and sz = silu(za)
// M=2052, N=1024, K=256. BM=64 BN=64 BK=32, 256 thr, 4x4/thread.
// ---------------------------------------------------------------------------
__global__ __launch_bounds__(256) void k1_gemm_in(
    const float* __restrict__ x, const float* __restrict__ w,
    float* __restrict__ xa, float* __restrict__ sz) {
  __shared__ float As[32][68];
  __shared__ float Bs[32][68];
  const int t = threadIdx.x;
  const int tx = t & 15, ty = t >> 4;
  const int m0 = blockIdx.x * 64, n0 = blockIdx.y * 64;
  float acc[4][4] = {};
  for (int k0 = 0; k0 < 256; k0 += 32) {
    #pragma unroll
    for (int p = 0; p < 2; ++p) {
      int f = t + p * 256;            // 0..511
      int row = f >> 3, cf = f & 7;   // 64 rows x 8 float4
      int gr = m0 + row; gr = gr < MM ? gr : MM - 1;
      float4 v = *(const float4*)(x + (size_t)gr * 256 + k0 + cf * 4);
      As[cf*4+0][row] = v.x; As[cf*4+1][row] = v.y;
      As[cf*4+2][row] = v.z; As[cf*4+3][row] = v.w;
      int gn = n0 + row;
      float4 u = *(const float4*)(w + (size_t)gn * 256 + k0 + cf * 4);
      Bs[cf*4+0][row] = u.x; Bs[cf*4+1][row] = u.y;
      Bs[cf*4+2][row] = u.z; Bs[cf*4+3][row] = u.w;
    }
    __syncthreads();
    #pragma unroll
    for (int k = 0; k < 32; ++k) {
      float4 av = *(const float4*)&As[k][ty*4];
      float4 bv = *(const float4*)&Bs[k][tx*4];
      float a0 = av.x, a1 = av.y, a2 = av.z, a3 = av.w;
      float b0 = bv.x, b1 = bv.y, b2 = bv.z, b3 = bv.w;
      acc[0][0]=fmaf(a0,b0,acc[0][0]); acc[0][1]=fmaf(a0,b1,acc[0][1]); acc[0][2]=fmaf(a0,b2,acc[0][2]); acc[0][3]=fmaf(a0,b3,acc[0][3]);
      acc[1][0]=fmaf(a1,b0,acc[1][0]); acc[1][1]=fmaf(a1,b1,acc[1][1]); acc[1][2]=fmaf(a1,b2,acc[1][2]); acc[1][3]=fmaf(a1,b3,acc[1][3]);
      acc[2][0]=fmaf(a2,b0,acc[2][0]); acc[2][1]=fmaf(a2,b1,acc[2][1]); acc[2][2]=fmaf(a2,b2,acc[2][2]); acc[2][3]=fmaf(a2,b3,acc[2][3]);
      acc[3][0]=fmaf(a3,b0,acc[3][0]); acc[3][1]=fmaf(a3,b1,acc[3][1]); acc[3][2]=fmaf(a3,b2,acc[3][2]); acc[3][3]=fmaf(a3,b3,acc[3][3]);
    }
    __syncthreads();
  }
  #pragma unroll
  for (int i = 0; i < 4; ++i) {
    int gm = m0 + ty*4 + i;
    if (gm < MM) {
      #pragma unroll
      for (int j = 0; j < 4; ++j) {
        int gn = n0 + tx*4 + j;
        float v = acc[i][j];
        if (gn < 512) xa[(size_t)gm*512 + gn] = v;
        else          sz[(size_t)gm*512 + gn - 512] = silu_f(v);
      }
    }
  }
}

// ---------------------------------------------------------------------------
// k2: per-branch conv(K=4)+silu -> xac ; dBC = xc @ xpw^T ; delta; store B,C.
// 16-row tiles (round-4 structure: best measured). Weights direct from
// global (16-lane-shared addresses, L2 resident). Fast transcendentals.
// br==0 blocks additionally zero acc[] for k3b's atomic accumulation.
// ---------------------------------------------------------------------------
__global__ __launch_bounds__(256) void k2_branch(
    Params P, const float* __restrict__ xa,
    float* __restrict__ xac, float* __restrict__ delta, float* __restrict__ bcg,
    float* __restrict__ acc_out) {
  __shared__ float xcS[16][516];      // 516 % 32 = 4 -> 2-way (free) aliasing
  __shared__ float dBCs[16][49];
  const int t = threadIdx.x;
  const int l0 = blockIdx.x * 16;
  const int b  = blockIdx.y;
  const int br = blockIdx.z;
  const int e0 = 2 * t;

  // zero the shared accumulator (done by branch-0 blocks; k3b runs later)
  if (br == 0) {
    float* ab = acc_out + ((size_t)b * LL + l0) * 512;
    int nmax = (LL - l0 < 16 ? LL - l0 : 16) * 512;
    for (int idx = t; idx < nmax; idx += 256) ab[idx] = 0.f;
  }

  const float* cw = P.cw[br];
  const float w00 = cw[e0*4+0], w01 = cw[e0*4+1], w02 = cw[e0*4+2], w03 = cw[e0*4+3];
  const float w10 = cw[(e0+1)*4+0], w11 = cw[(e0+1)*4+1], w12 = cw[(e0+1)*4+2], w13 = cw[(e0+1)*4+3];
  const float cb0 = P.cb[br][e0], cb1 = P.cb[br][e0+1];
  const float* xab = xa + (size_t)b * LL * 512;
  const size_t obase = (size_t)(br*2 + b) * LL;

  float h0x=0,h0y=0,h1x=0,h1y=0,h2x=0,h2y=0,h3x=0,h3y=0;
  for (int i = -3; i < 16; ++i) {
    int l = l0 + i;
    float cx = 0.f, cy = 0.f;
    if (l >= 0 && l < LL) {
      int pos = sigma_map(br, l);
      float2 v = *(const float2*)(xab + (size_t)pos * 512 + e0);
      cx = v.x; cy = v.y;
    }
    h0x=h1x; h0y=h1y; h1x=h2x; h1y=h2y; h2x=h3x; h2y=h3y; h3x=cx; h3y=cy;
    if (i >= 0) {
      float o0 = fmaf(w00,h0x, fmaf(w01,h1x, fmaf(w02,h2x, fmaf(w03,h3x, cb0))));
      float o1 = fmaf(w10,h0y, fmaf(w11,h1y, fmaf(w12,h2y, fmaf(w13,h3y, cb1))));
      o0 = silu_f(o0); o1 = silu_f(o1);
      *(float2*)&xcS[i][e0] = make_float2(o0, o1);
      if (l < LL)
        *(float2*)(xac + (obase + l) * 512 + e0) = make_float2(o0, o1);
    }
  }
  __syncthreads();

  // projection: thread -> (row = t&15, r-cols r0, r0+16, r0+32), K=512 one pass
  const int rowi = t & 15;
  const int r0 = t >> 4;
  const float* xpw = P.xpw[br];
  const float4* xr4 = (const float4*)&xcS[rowi][0];
  const float4* wa = (const float4*)(xpw + (size_t)r0 * 512);
  const float4* wb = (const float4*)(xpw + (size_t)(r0 + 16) * 512);
  const float4* wc = (const float4*)(xpw + (size_t)(r0 + 32) * 512);
  float acc0 = 0.f, acc1 = 0.f, acc2 = 0.f;
  #pragma unroll 8
  for (int e4 = 0; e4 < 128; ++e4) {
    float4 xv = xr4[e4];
    float4 a = wa[e4], bb = wb[e4], c = wc[e4];
    acc0 = fmaf(xv.x,a.x, fmaf(xv.y,a.y, fmaf(xv.z,a.z, fmaf(xv.w,a.w, acc0))));
    acc1 = fmaf(xv.x,bb.x,fmaf(xv.y,bb.y,fmaf(xv.z,bb.z,fmaf(xv.w,bb.w,acc1))));
    acc2 = fmaf(xv.x,c.x, fmaf(xv.y,c.y, fmaf(xv.z,c.z, fmaf(xv.w,c.w, acc2))));
  }
  dBCs[rowi][r0]      = acc0;
  dBCs[rowi][r0 + 16] = acc1;
  dBCs[rowi][r0 + 32] = acc2;
  __syncthreads();

  // store B, C
  for (int idx = t; idx < 512; idx += 256) {
    int row = idx >> 5, c = idx & 31;
    int l = l0 + row;
    if (l < LL) bcg[(obase + l)*32 + c] = dBCs[row][16 + c];
  }

  // delta = softplus(dBC[:, :16] @ dtw^T + dtb)
  const float* dtw = P.dtw[br];
  float dw0[16], dw1[16];
  #pragma unroll
  for (int r = 0; r < 16; ++r) { dw0[r] = dtw[e0*16 + r]; dw1[r] = dtw[(e0+1)*16 + r]; }
  const float db0 = P.dtb[br][e0], db1 = P.dtb[br][e0+1];
  for (int row = 0; row < 16; ++row) {
    int l = l0 + row;
    if (l >= LL) break;
    float s0 = db0, s1 = db1;
    #pragma unroll
    for (int r = 0; r < 16; ++r) {
      float d = dBCs[row][r];
      s0 = fmaf(d, dw0[r], s0);
      s1 = fmaf(d, dw1[r], s1);
    }
    *(float2*)(delta + (obase + l)*512 + e0) = make_float2(softplus_f(s0), softplus_f(s1));
  }
}

// ---------------------------------------------------------------------------
// k3a: per-chunk scan summaries. For chunk c of chain (br,b,e,n):
//   P_c = prod da = exp(A_en * sum delta), Q_c = chunk-local scan (h_in = 0).
// ---------------------------------------------------------------------------
__global__ __launch_bounds__(256) void k3a_chunk(
    Params P, const float* __restrict__ xac, const float* __restrict__ delta,
    const float* __restrict__ bcg, float* __restrict__ Pc, float* __restrict__ Qc) {
  __shared__ float dT[16][33], xT[16][33], bT[16][33];
  const int t = threadIdx.x;
  const int eL = t >> 4, n = t & 15;
  const int e0 = blockIdx.x * 16;
  const int b = blockIdx.y;
  const int br = blockIdx.z / NC, c = blockIdx.z % NC;
  const size_t sbase = (size_t)(br*2 + b) * LL;
  const float* dl = delta + sbase * 512;
  const float* xc = xac + sbase * 512;
  const float* bc = bcg + sbase * 32;
  const float A_en = -__expf(P.Al[br][(e0 + eL)*16 + n]);
  const int l0 = c * LC;
  const int lend = (c == NC-1) ? LL : (l0 + LC);
  float h = 0.f, dsum = 0.f;

  for (int c0 = l0; c0 < lend; c0 += 32) {
    #pragma unroll
    for (int p = 0; p < 2; ++p) {
      int idx = t + p*256;
      int s = idx >> 4, ee = idx & 15;
      int l = c0 + s;
      float dv = 0.f, xv = 0.f, bv = 0.f;
      if (l < lend) {
        dv = dl[(size_t)l*512 + e0 + ee];
        xv = xc[(size_t)l*512 + e0 + ee];
        bv = bc[l*32 + ee];
      }
      dT[ee][s] = dv; xT[ee][s] = xv; bT[ee][s] = bv;
    }
    __syncthreads();
    float da[32], dbx[32];
    #pragma unroll
    for (int s = 0; s < 32; ++s) {
      float d = dT[eL][s];
      da[s]  = __expf(d * A_en);           // d=0 pad -> 1 (identity)
      dbx[s] = d * xT[eL][s] * bT[n][s];   // pad -> 0
      dsum += d;
    }
    #pragma unroll
    for (int s = 0; s < 32; ++s) h = fmaf(da[s], h, dbx[s]);
    __syncthreads();
  }
  size_t oi = ((((size_t)(br*2 + b)*NC + c)*32 + blockIdx.x)*256 + t);
  Pc[oi] = __expf(dsum * A_en);
  Qc[oi] = h;
}

// ---------------------------------------------------------------------------
// k3b: chunk-parallel output scan. h_in from preceding (P,Q) pairs, local
// scan produces y ; gated result ATOMICALLY accumulated (x0.25) into acc.
// ---------------------------------------------------------------------------
__global__ __launch_bounds__(256) void k3b_scan(
    Params P, const float* __restrict__ xac, const float* __restrict__ delta,
    const float* __restrict__ bcg, const float* __restrict__ sz,
    const float* __restrict__ Pc, const float* __restrict__ Qc,
    float* __restrict__ acc_out) {
  __shared__ float dT[16][33], xT[16][33], bT[16][33], cT[16][33];
  __shared__ float ybuf[32][17];
  const int t = threadIdx.x;
  const int eL = t >> 4, n = t & 15;
  const int e0 = blockIdx.x * 16;
  const int b = blockIdx.y;
  const int br = blockIdx.z / NC, c = blockIdx.z % NC;
  const size_t sbase = (size_t)(br*2 + b) * LL;
  const float* dl = delta + sbase * 512;
  const float* xc = xac + sbase * 512;
  const float* bc = bcg + sbase * 32;
  const float A_en = -__expf(P.Al[br][(e0 + eL)*16 + n]);
  const float Dval = P.Dp[br][e0 + (t & 15)];
  const float* szb = sz + (size_t)b * LL * 512;
  float* ab = acc_out + (size_t)b * LL * 512;

  // h_in for this chunk: h[c] = P[c-1]*h[c-1] + Q[c-1], h[0]=0
  float h = 0.f;
  for (int cc = 0; cc < c; ++cc) {
    size_t ii = ((((size_t)(br*2 + b)*NC + cc)*32 + blockIdx.x)*256 + t);
    h = fmaf(Pc[ii], h, Qc[ii]);
  }

  const int l0c = c * LC;
  const int lend = (c == NC-1) ? LL : (l0c + LC);
  for (int c0 = l0c; c0 < lend; c0 += 32) {
    #pragma unroll
    for (int p = 0; p < 2; ++p) {
      int idx = t + p*256;
      int s = idx >> 4, ee = idx & 15;
      int l = c0 + s;
      float dv = 0.f, xv = 0.f, bv = 0.f, cv = 0.f;
      if (l < lend) {
        dv = dl[(size_t)l*512 + e0 + ee];
        xv = xc[(size_t)l*512 + e0 + ee];
        bv = bc[l*32 + ee];
        cv = bc[l*32 + 16 + ee];
      }
      dT[ee][s] = dv; xT[ee][s] = xv; bT[ee][s] = bv; cT[ee][s] = cv;
    }
    __syncthreads();

    float da[32], dbx[32], ccv[32];
    #pragma unroll
    for (int s = 0; s < 32; ++s) {
      float d  = dT[eL][s];
      float xv = xT[eL][s];
      da[s]  = __expf(d * A_en);
      dbx[s] = d * xv * bT[n][s];
      ccv[s] = cT[n][s];
    }
    #pragma unroll
    for (int s = 0; s < 32; ++s) {
      h = fmaf(da[s], h, dbx[s]);
      float r = h * ccv[s];
      r += dpp_mov0<0xB1>(r);    // quad_perm xor1
      r += dpp_mov0<0x4E>(r);    // quad_perm xor2
      r += dpp_mov0<0x114>(r);   // row_shr:4
      r += dpp_mov0<0x118>(r);   // row_shr:8 -> lane 15 of each 16 holds sum
      if (n == 15) ybuf[s][eL] = r;
    }
    __syncthreads();

    #pragma unroll
    for (int p = 0; p < 2; ++p) {
      int idx = t + p*256;
      int s = idx >> 4, ee = idx & 15;
      int l = c0 + s;
      if (l < lend) {
        float yv = fmaf(Dval, xT[ee][s], ybuf[s][ee]);
        int pos = sigma_map(br, l);
        float szv = szb[(size_t)pos * 512 + e0 + ee];
        atomicAdd(ab + (size_t)pos * 512 + e0 + ee, 0.25f * yv * szv);
      }
    }
    __syncthreads();
  }
}

// ---------------------------------------------------------------------------
// k4: out = acc @ out_w^T.  M=2052 N=256 K=512. (0.25 & branch-sum folded
// into acc by k3b.)  BM=32 BN=32 BK=32, 2x2/thread.
// ---------------------------------------------------------------------------
__global__ __launch_bounds__(256) void k4_gemm_out(
    const float* __restrict__ acc_in, const float* __restrict__ w,
    float* __restrict__ out) {
  __shared__ float As[32][38];
  __shared__ float Bs[32][38];
  const int t = threadIdx.x;
  const int tx = t & 15, ty = t >> 4;
  const int m0 = blockIdx.x * 32, n0 = blockIdx.y * 32;
  float acc[2][2] = {};
  for (int k0 = 0; k0 < 512; k0 += 32) {
    #pragma unroll
    for (int p = 0; p < 4; ++p) {
      int idx = t + p*256;
      int row = idx >> 5, kk = idx & 31;
      int gm = m0 + row; gm = gm < MM ? gm : MM - 1;
      As[kk][row] = acc_in[(size_t)gm*512 + k0 + kk];
    }
    #pragma unroll
    for (int p = 0; p < 4; ++p) {
      int idx = t + p*256;
      int row = idx >> 5, kk = idx & 31;
      Bs[kk][row] = w[(size_t)(n0 + row)*512 + k0 + kk];
    }
    __syncthreads();
    #pragma unroll
    for (int k = 0; k < 32; ++k) {
      float2 av = *(const float2*)&As[k][ty*2];
      float2 bv = *(const float2*)&Bs[k][tx*2];
      acc[0][0]=fmaf(av.x,bv.x,acc[0][0]); acc[0][1]=fmaf(av.x,bv.y,acc[0][1]);
      acc[1][0]=fmaf(av.y,bv.x,acc[1][0]); acc[1][1]=fmaf(av.y,bv.y,acc[1][1]);
    }
    __syncthreads();
  }
  #pragma unroll
  for (int i = 0; i < 2; ++i) {
    int gm = m0 + ty*2 + i;
    if (gm < MM) {
      #pragma unroll
      for (int j = 0; j < 2; ++j)
        out[(size_t)gm*256 + n0 + tx*2 + j] = acc[i][j];
    }
  }
}

// ---------------------------------------------------------------------------
extern "C" void kernel_launch(void* const* d_in, const int* in_sizes, int n_in,
                              void* d_out, int out_size, void* d_ws, size_t ws_size,
                              hipStream_t stream) {
  const float* x    = (const float*)d_in[0];
  const float* in_w = (const float*)d_in[1];
  const float* out_w= (const float*)d_in[2];
  Params prm;
  for (int s = 0; s < 4; ++s) {
    prm.cw[s]  = (const float*)d_in[3 + s*7 + 0];
    prm.cb[s]  = (const float*)d_in[3 + s*7 + 1];
    prm.xpw[s] = (const float*)d_in[3 + s*7 + 2];
    prm.dtw[s] = (const float*)d_in[3 + s*7 + 3];
    prm.dtb[s] = (const float*)d_in[3 + s*7 + 4];
    prm.Al[s]  = (const float*)d_in[3 + s*7 + 5];
    prm.Dp[s]  = (const float*)d_in[3 + s*7 + 6];
  }
  float* ws = (float*)d_ws;
  const size_t SZ1 = (size_t)MM * 512;        // 1,050,624 floats
  float* xa   = ws;                            // [MM][512] (reused as Pc/Qc after k2)
  float* szp  = ws + SZ1;                      // [MM][512]
  float* xac  = ws + 2*SZ1;                    // [4][MM][512] branch-ordered
  float* dlt  = ws + 6*SZ1;                    // [4][MM][512]
  float* bc   = ws + 10*SZ1;                   // [4][MM][32]
  float* acc  = ws + 10*SZ1 + (size_t)4*MM*32; // [MM][512]  summed gated output
  // Pc/Qc overlay xa (dead after k2): 8*NC*32*256 = 524288 floats each
  float* Pc = xa;
  float* Qc = xa + (size_t)8*NC*32*256;

  k1_gemm_in<<<dim3(33, 16), 256, 0, stream>>>(x, in_w, xa, szp);
  k2_branch <<<dim3(65, 2, 4), 256, 0, stream>>>(prm, xa, xac, dlt, bc, acc);
  k3a_chunk <<<dim3(32, 2, 4*NC), 256, 0, stream>>>(prm, xac, dlt, bc, Pc, Qc);
  k3b_scan  <<<dim3(32, 2, 4*NC), 256, 0, stream>>>(prm, xac, dlt, bc, szp, Pc, Qc, acc);
  k4_gemm_out<<<dim3(65, 8), 256, 0, stream>>>(acc, out_w, (float*)d_out);
}

// Round 8
// 279.282 us; speedup vs baseline: 1.1835x; 1.0757x over previous
//
#include <hip/hip_runtime.h>
#include <math.h>

#define LL 1026          // sequence length S*S+2
#define EDim 512
#define MM 2052          // B0*LL
#define NC 16            // scan chunks (last chunk = 66 steps, others 64)
#define LC 64

struct Params {
  const float* cw[4];
  const float* cb[4];
  const float* xpw[4];
  const float* dtw[4];
  const float* dtb[4];
  const float* Al[4];
  const float* Dp[4];
};

// branch position l -> original position
__device__ __forceinline__ int sigma_map(int branch, int l) {
  if (branch & 1) l = LL - 1 - l;          // reverse
  if (branch & 2) {                        // S x S transpose of inner block
    if (l > 0 && l < LL - 1) {
      int p = l - 1;
      l = 1 + ((p & 31) << 5) + (p >> 5);
    }
  }
  return l;
}

__device__ __forceinline__ float silu_f(float v) {
  return v * __builtin_amdgcn_rcpf(1.f + __expf(-v));
}
__device__ __forceinline__ float softplus_f(float s) {
  return fmaxf(s, 0.f) + __logf(1.f + __expf(-fabsf(s)));
}

template<int CTRL>
__device__ __forceinline__ float dpp_mov0(float x) {
  int r = __builtin_amdgcn_update_dpp(0, __float_as_int(x), CTRL, 0xF, 0xF, false);
  return __int_as_float(r);
}

// 16-lane sum, result valid in lane 15 of each 16-lane group
__device__ __forceinline__ float red16(float r) {
  r += dpp_mov0<0xB1>(r);    // quad_perm xor1
  r += dpp_mov0<0x4E>(r);    // quad_perm xor2
  r += dpp_mov0<0x114>(r);   // row_shr:4
  r += dpp_mov0<0x118>(r);   // row_shr:8
  return r;
}

// ---------------------------------------------------------------------------
// k1: xz = x @ in_w^T ; split into xa (cols 0..511) and sz = silu(za)
// ---------------------------------------------------------------------------
__global__ __launch_bounds__(256) void k1_gemm_in(
    const float* __restrict__ x, const float* __restrict__ w,
    float* __restrict__ xa, float* __restrict__ sz) {
  __shared__ float As[32][68];
  __shared__ float Bs[32][68];
  const int t = threadIdx.x;
  const int tx = t & 15, ty = t >> 4;
  const int m0 = blockIdx.x * 64, n0 = blockIdx.y * 64;
  float acc[4][4] = {};
  for (int k0 = 0; k0 < 256; k0 += 32) {
    #pragma unroll
    for (int p = 0; p < 2; ++p) {
      int f = t + p * 256;            // 0..511
      int row = f >> 3, cf = f & 7;   // 64 rows x 8 float4
      int gr = m0 + row; gr = gr < MM ? gr : MM - 1;
      float4 v = *(const float4*)(x + (size_t)gr * 256 + k0 + cf * 4);
      As[cf*4+0][row] = v.x; As[cf*4+1][row] = v.y;
      As[cf*4+2][row] = v.z; As[cf*4+3][row] = v.w;
      int gn = n0 + row;
      float4 u = *(const float4*)(w + (size_t)gn * 256 + k0 + cf * 4);
      Bs[cf*4+0][row] = u.x; Bs[cf*4+1][row] = u.y;
      Bs[cf*4+2][row] = u.z; Bs[cf*4+3][row] = u.w;
    }
    __syncthreads();
    #pragma unroll
    for (int k = 0; k < 32; ++k) {
      float4 av = *(const float4*)&As[k][ty*4];
      float4 bv = *(const float4*)&Bs[k][tx*4];
      float a0 = av.x, a1 = av.y, a2 = av.z, a3 = av.w;
      float b0 = bv.x, b1 = bv.y, b2 = bv.z, b3 = bv.w;
      acc[0][0]=fmaf(a0,b0,acc[0][0]); acc[0][1]=fmaf(a0,b1,acc[0][1]); acc[0][2]=fmaf(a0,b2,acc[0][2]); acc[0][3]=fmaf(a0,b3,acc[0][3]);
      acc[1][0]=fmaf(a1,b0,acc[1][0]); acc[1][1]=fmaf(a1,b1,acc[1][1]); acc[1][2]=fmaf(a1,b2,acc[1][2]); acc[1][3]=fmaf(a1,b3,acc[1][3]);
      acc[2][0]=fmaf(a2,b0,acc[2][0]); acc[2][1]=fmaf(a2,b1,acc[2][1]); acc[2][2]=fmaf(a2,b2,acc[2][2]); acc[2][3]=fmaf(a2,b3,acc[2][3]);
      acc[3][0]=fmaf(a3,b0,acc[3][0]); acc[3][1]=fmaf(a3,b1,acc[3][1]); acc[3][2]=fmaf(a3,b2,acc[3][2]); acc[3][3]=fmaf(a3,b3,acc[3][3]);
    }
    __syncthreads();
  }
  #pragma unroll
  for (int i = 0; i < 4; ++i) {
    int gm = m0 + ty*4 + i;
    if (gm < MM) {
      #pragma unroll
      for (int j = 0; j < 4; ++j) {
        int gn = n0 + tx*4 + j;
        float v = acc[i][j];
        if (gn < 512) xa[(size_t)gm*512 + gn] = v;
        else          sz[(size_t)gm*512 + gn - 512] = silu_f(v);
      }
    }
  }
}

// ---------------------------------------------------------------------------
// k2: per-branch conv(K=4)+silu -> xac ; dBC = xc @ xpw^T ; delta; store B,C.
// br==0 blocks zero acc[] for k3b's atomic accumulation.
// ---------------------------------------------------------------------------
__global__ __launch_bounds__(256) void k2_branch(
    Params P, const float* __restrict__ xa,
    float* __restrict__ xac, float* __restrict__ delta, float* __restrict__ bcg,
    float* __restrict__ acc_out) {
  __shared__ float xcS[16][516];
  __shared__ float dBCs[16][49];
  const int t = threadIdx.x;
  const int l0 = blockIdx.x * 16;
  const int b  = blockIdx.y;
  const int br = blockIdx.z;
  const int e0 = 2 * t;

  if (br == 0) {
    float* ab = acc_out + ((size_t)b * LL + l0) * 512;
    int nmax = (LL - l0 < 16 ? LL - l0 : 16) * 512;
    for (int idx = t; idx < nmax; idx += 256) ab[idx] = 0.f;
  }

  const float* cw = P.cw[br];
  const float w00 = cw[e0*4+0], w01 = cw[e0*4+1], w02 = cw[e0*4+2], w03 = cw[e0*4+3];
  const float w10 = cw[(e0+1)*4+0], w11 = cw[(e0+1)*4+1], w12 = cw[(e0+1)*4+2], w13 = cw[(e0+1)*4+3];
  const float cb0 = P.cb[br][e0], cb1 = P.cb[br][e0+1];
  const float* xab = xa + (size_t)b * LL * 512;
  const size_t obase = (size_t)(br*2 + b) * LL;

  float h0x=0,h0y=0,h1x=0,h1y=0,h2x=0,h2y=0,h3x=0,h3y=0;
  for (int i = -3; i < 16; ++i) {
    int l = l0 + i;
    float cx = 0.f, cy = 0.f;
    if (l >= 0 && l < LL) {
      int pos = sigma_map(br, l);
      float2 v = *(const float2*)(xab + (size_t)pos * 512 + e0);
      cx = v.x; cy = v.y;
    }
    h0x=h1x; h0y=h1y; h1x=h2x; h1y=h2y; h2x=h3x; h2y=h3y; h3x=cx; h3y=cy;
    if (i >= 0) {
      float o0 = fmaf(w00,h0x, fmaf(w01,h1x, fmaf(w02,h2x, fmaf(w03,h3x, cb0))));
      float o1 = fmaf(w10,h0y, fmaf(w11,h1y, fmaf(w12,h2y, fmaf(w13,h3y, cb1))));
      o0 = silu_f(o0); o1 = silu_f(o1);
      *(float2*)&xcS[i][e0] = make_float2(o0, o1);
      if (l < LL)
        *(float2*)(xac + (obase + l) * 512 + e0) = make_float2(o0, o1);
    }
  }
  __syncthreads();

  const int rowi = t & 15;
  const int r0 = t >> 4;
  const float* xpw = P.xpw[br];
  const float4* xr4 = (const float4*)&xcS[rowi][0];
  const float4* wa = (const float4*)(xpw + (size_t)r0 * 512);
  const float4* wb = (const float4*)(xpw + (size_t)(r0 + 16) * 512);
  const float4* wc = (const float4*)(xpw + (size_t)(r0 + 32) * 512);
  float acc0 = 0.f, acc1 = 0.f, acc2 = 0.f;
  #pragma unroll 8
  for (int e4 = 0; e4 < 128; ++e4) {
    float4 xv = xr4[e4];
    float4 a = wa[e4], bb = wb[e4], c = wc[e4];
    acc0 = fmaf(xv.x,a.x, fmaf(xv.y,a.y, fmaf(xv.z,a.z, fmaf(xv.w,a.w, acc0))));
    acc1 = fmaf(xv.x,bb.x,fmaf(xv.y,bb.y,fmaf(xv.z,bb.z,fmaf(xv.w,bb.w,acc1))));
    acc2 = fmaf(xv.x,c.x, fmaf(xv.y,c.y, fmaf(xv.z,c.z, fmaf(xv.w,c.w, acc2))));
  }
  dBCs[rowi][r0]      = acc0;
  dBCs[rowi][r0 + 16] = acc1;
  dBCs[rowi][r0 + 32] = acc2;
  __syncthreads();

  for (int idx = t; idx < 512; idx += 256) {
    int row = idx >> 5, c = idx & 31;
    int l = l0 + row;
    if (l < LL) bcg[(obase + l)*32 + c] = dBCs[row][16 + c];
  }

  const float* dtw = P.dtw[br];
  float dw0[16], dw1[16];
  #pragma unroll
  for (int r = 0; r < 16; ++r) { dw0[r] = dtw[e0*16 + r]; dw1[r] = dtw[(e0+1)*16 + r]; }
  const float db0 = P.dtb[br][e0], db1 = P.dtb[br][e0+1];
  for (int row = 0; row < 16; ++row) {
    int l = l0 + row;
    if (l >= LL) break;
    float s0 = db0, s1 = db1;
    #pragma unroll
    for (int r = 0; r < 16; ++r) {
      float d = dBCs[row][r];
      s0 = fmaf(d, dw0[r], s0);
      s1 = fmaf(d, dw1[r], s1);
    }
    *(float2*)(delta + (obase + l)*512 + e0) = make_float2(softplus_f(s0), softplus_f(s1));
  }
}

// ---------------------------------------------------------------------------
// k3a: per-chunk scan summaries.  P_c = exp(A_en * sum delta), Q_c = local
// scan (h_in=0).  float4 staging, b128 LDS reads, 4-step register batches.
// ---------------------------------------------------------------------------
__global__ __launch_bounds__(256) void k3a_chunk(
    Params P, const float* __restrict__ xac, const float* __restrict__ delta,
    const float* __restrict__ bcg, float* __restrict__ Pc, float* __restrict__ Qc) {
  __shared__ float dT[16][36], xT[16][36], bT[16][36];
  const int t = threadIdx.x;
  const int eL = t >> 4, n = t & 15;
  const int e0 = blockIdx.x * 16;
  const int b = blockIdx.y;
  const int br = blockIdx.z / NC, c = blockIdx.z % NC;
  const size_t sbase = (size_t)(br*2 + b) * LL;
  const float* dl = delta + sbase * 512;
  const float* xc = xac + sbase * 512;
  const float* bc = bcg + sbase * 32;
  const float A_en = -__expf(P.Al[br][(e0 + eL)*16 + n]);
  const int l0 = c * LC;
  const int lend = (c == NC-1) ? LL : (l0 + LC);
  float h = 0.f, dsum = 0.f;

  for (int c0 = l0; c0 < lend; c0 += 32) {
    {
      const int idx = t & 127;
      const int s = idx >> 2, q = idx & 3;
      const int l = c0 + s;
      float4 v = make_float4(0.f,0.f,0.f,0.f);
      if (t < 128) {
        if (l < lend) v = *(const float4*)(dl + (size_t)l*512 + e0 + q*4);
        dT[q*4+0][s]=v.x; dT[q*4+1][s]=v.y; dT[q*4+2][s]=v.z; dT[q*4+3][s]=v.w;
        float4 u = make_float4(0.f,0.f,0.f,0.f);
        if (l < lend) u = *(const float4*)(bc + (size_t)l*32 + q*4);
        bT[q*4+0][s]=u.x; bT[q*4+1][s]=u.y; bT[q*4+2][s]=u.z; bT[q*4+3][s]=u.w;
      } else {
        if (l < lend) v = *(const float4*)(xc + (size_t)l*512 + e0 + q*4);
        xT[q*4+0][s]=v.x; xT[q*4+1][s]=v.y; xT[q*4+2][s]=v.z; xT[q*4+3][s]=v.w;
      }
    }
    __syncthreads();
    #pragma unroll
    for (int s4 = 0; s4 < 32; s4 += 4) {
      float4 dv = *(const float4*)&dT[eL][s4];
      float4 xv = *(const float4*)&xT[eL][s4];
      float4 bv = *(const float4*)&bT[n][s4];
      float g0 = __expf(dv.x*A_en), g1 = __expf(dv.y*A_en);
      float g2 = __expf(dv.z*A_en), g3 = __expf(dv.w*A_en);
      dsum += (dv.x+dv.y)+(dv.z+dv.w);
      h = fmaf(g0, h, dv.x*xv.x*bv.x);
      h = fmaf(g1, h, dv.y*xv.y*bv.y);
      h = fmaf(g2, h, dv.z*xv.z*bv.z);
      h = fmaf(g3, h, dv.w*xv.w*bv.w);
    }
    __syncthreads();
  }
  size_t oi = ((((size_t)(br*2 + b)*NC + c)*32 + blockIdx.x)*256 + t);
  Pc[oi] = __expf(dsum * A_en);
  Qc[oi] = h;
}

// ---------------------------------------------------------------------------
// k3b: chunk-parallel output scan; gated result atomically accumulated
// (x0.25) into acc.  Same vectorized staging/read structure as k3a.
// ---------------------------------------------------------------------------
__global__ __launch_bounds__(256) void k3b_scan(
    Params P, const float* __restrict__ xac, const float* __restrict__ delta,
    const float* __restrict__ bcg, const float* __restrict__ sz,
    const float* __restrict__ Pc, const float* __restrict__ Qc,
    float* __restrict__ acc_out) {
  __shared__ float dT[16][36], xT[16][36], bT[16][36], cT[16][36];
  __shared__ float yb[16][36];
  const int t = threadIdx.x;
  const int eL = t >> 4, n = t & 15;
  const int e0 = blockIdx.x * 16;
  const int b = blockIdx.y;
  const int br = blockIdx.z / NC, c = blockIdx.z % NC;
  const size_t sbase = (size_t)(br*2 + b) * LL;
  const float* dl = delta + sbase * 512;
  const float* xc = xac + sbase * 512;
  const float* bc = bcg + sbase * 32;
  const float A_en = -__expf(P.Al[br][(e0 + eL)*16 + n]);
  const float Dval = P.Dp[br][e0 + (t & 15)];
  const float* szb = sz + (size_t)b * LL * 512;
  float* ab = acc_out + (size_t)b * LL * 512;

  // h_in: h[c] = P[c-1]*h[c-1] + Q[c-1], h[0]=0
  float h = 0.f;
  for (int cc = 0; cc < c; ++cc) {
    size_t ii = ((((size_t)(br*2 + b)*NC + cc)*32 + blockIdx.x)*256 + t);
    h = fmaf(Pc[ii], h, Qc[ii]);
  }

  const int l0c = c * LC;
  const int lend = (c == NC-1) ? LL : (l0c + LC);
  for (int c0 = l0c; c0 < lend; c0 += 32) {
    {
      const int idx = t & 127;
      const int s = idx >> 2, q = idx & 3;
      const int l = c0 + s;
      float4 v = make_float4(0.f,0.f,0.f,0.f);
      if (t < 128) {
        if (l < lend) v = *(const float4*)(dl + (size_t)l*512 + e0 + q*4);
        dT[q*4+0][s]=v.x; dT[q*4+1][s]=v.y; dT[q*4+2][s]=v.z; dT[q*4+3][s]=v.w;
      } else {
        if (l < lend) v = *(const float4*)(xc + (size_t)l*512 + e0 + q*4);
        xT[q*4+0][s]=v.x; xT[q*4+1][s]=v.y; xT[q*4+2][s]=v.z; xT[q*4+3][s]=v.w;
      }
    }
    {
      const int s = t >> 3, q = t & 7;
      const int l = c0 + s;
      float4 u = make_float4(0.f,0.f,0.f,0.f);
      if (l < lend) u = *(const float4*)(bc + (size_t)l*32 + q*4);
      if (q < 4) {
        bT[q*4+0][s]=u.x; bT[q*4+1][s]=u.y; bT[q*4+2][s]=u.z; bT[q*4+3][s]=u.w;
      } else {
        int q4 = (q-4)*4;
        cT[q4+0][s]=u.x; cT[q4+1][s]=u.y; cT[q4+2][s]=u.z; cT[q4+3][s]=u.w;
      }
    }
    __syncthreads();

    #pragma unroll
    for (int s4 = 0; s4 < 32; s4 += 4) {
      float4 dv = *(const float4*)&dT[eL][s4];
      float4 xv = *(const float4*)&xT[eL][s4];
      float4 bv = *(const float4*)&bT[n][s4];
      float4 cv = *(const float4*)&cT[n][s4];
      float r0, r1, r2, r3;
      h = fmaf(__expf(dv.x*A_en), h, dv.x*xv.x*bv.x); r0 = red16(h*cv.x);
      h = fmaf(__expf(dv.y*A_en), h, dv.y*xv.y*bv.y); r1 = red16(h*cv.y);
      h = fmaf(__expf(dv.z*A_en), h, dv.z*xv.z*bv.z); r2 = red16(h*cv.z);
      h = fmaf(__expf(dv.w*A_en), h, dv.w*xv.w*bv.w); r3 = red16(h*cv.w);
      if (n == 15) *(float4*)&yb[eL][s4] = make_float4(r0, r1, r2, r3);
    }
    __syncthreads();

    #pragma unroll
    for (int p = 0; p < 2; ++p) {
      int idx = t + p*256;
      int s = idx >> 4, ee = idx & 15;
      int l = c0 + s;
      if (l < lend) {
        float yv = fmaf(Dval, xT[ee][s], yb[ee][s]);
        int pos = sigma_map(br, l);
        float szv = szb[(size_t)pos * 512 + e0 + ee];
        atomicAdd(ab + (size_t)pos * 512 + e0 + ee, 0.25f * yv * szv);
      }
    }
    __syncthreads();
  }
}

// ---------------------------------------------------------------------------
// k4: out = acc @ out_w^T.  M=2052 N=256 K=512.
// ---------------------------------------------------------------------------
__global__ __launch_bounds__(256) void k4_gemm_out(
    const float* __restrict__ acc_in, const float* __restrict__ w,
    float* __restrict__ out) {
  __shared__ float As[32][38];
  __shared__ float Bs[32][38];
  const int t = threadIdx.x;
  const int tx = t & 15, ty = t >> 4;
  const int m0 = blockIdx.x * 32, n0 = blockIdx.y * 32;
  float acc[2][2] = {};
  for (int k0 = 0; k0 < 512; k0 += 32) {
    #pragma unroll
    for (int p = 0; p < 4; ++p) {
      int idx = t + p*256;
      int row = idx >> 5, kk = idx & 31;
      int gm = m0 + row; gm = gm < MM ? gm : MM - 1;
      As[kk][row] = acc_in[(size_t)gm*512 + k0 + kk];
    }
    #pragma unroll
    for (int p = 0; p < 4; ++p) {
      int idx = t + p*256;
      int row = idx >> 5, kk = idx & 31;
      Bs[kk][row] = w[(size_t)(n0 + row)*512 + k0 + kk];
    }
    __syncthreads();
    #pragma unroll
    for (int k = 0; k < 32; ++k) {
      float2 av = *(const float2*)&As[k][ty*2];
      float2 bv = *(const float2*)&Bs[k][tx*2];
      acc[0][0]=fmaf(av.x,bv.x,acc[0][0]); acc[0][1]=fmaf(av.x,bv.y,acc[0][1]);
      acc[1][0]=fmaf(av.y,bv.x,acc[1][0]); acc[1][1]=fmaf(av.y,bv.y,acc[1][1]);
    }
    __syncthreads();
  }
  #pragma unroll
  for (int i = 0; i < 2; ++i) {
    int gm = m0 + ty*2 + i;
    if (gm < MM) {
      #pragma unroll
      for (int j = 0; j < 2; ++j)
        out[(size_t)gm*256 + n0 + tx*2 + j] = acc[i][j];
    }
  }
}

// ---------------------------------------------------------------------------
extern "C" void kernel_launch(void* const* d_in, const int* in_sizes, int n_in,
                              void* d_out, int out_size, void* d_ws, size_t ws_size,
                              hipStream_t stream) {
  const float* x    = (const float*)d_in[0];
  const float* in_w = (const float*)d_in[1];
  const float* out_w= (const float*)d_in[2];
  Params prm;
  for (int s = 0; s < 4; ++s) {
    prm.cw[s]  = (const float*)d_in[3 + s*7 + 0];
    prm.cb[s]  = (const float*)d_in[3 + s*7 + 1];
    prm.xpw[s] = (const float*)d_in[3 + s*7 + 2];
    prm.dtw[s] = (const float*)d_in[3 + s*7 + 3];
    prm.dtb[s] = (const float*)d_in[3 + s*7 + 4];
    prm.Al[s]  = (const float*)d_in[3 + s*7 + 5];
    prm.Dp[s]  = (const float*)d_in[3 + s*7 + 6];
  }
  float* ws = (float*)d_ws;
  const size_t SZ1 = (size_t)MM * 512;        // 1,050,624 floats
  float* xa   = ws;                            // [MM][512]
  float* szp  = ws + SZ1;                      // [MM][512]
  float* xac  = ws + 2*SZ1;                    // [4][MM][512] branch-ordered
  float* dlt  = ws + 6*SZ1;                    // [4][MM][512]
  float* bc   = ws + 10*SZ1;                   // [4][MM][32]
  float* acc  = ws + 10*SZ1 + (size_t)4*MM*32; // [MM][512]  summed gated output
  float* Pc   = acc + SZ1;                     // [8][NC][32][256] = 1,048,576
  float* Qc   = Pc + (size_t)8*NC*32*256;      // same size

  k1_gemm_in<<<dim3(33, 16), 256, 0, stream>>>(x, in_w, xa, szp);
  k2_branch <<<dim3(65, 2, 4), 256, 0, stream>>>(prm, xa, xac, dlt, bc, acc);
  k3a_chunk <<<dim3(32, 2, 4*NC), 256, 0, stream>>>(prm, xac, dlt, bc, Pc, Qc);
  k3b_scan  <<<dim3(32, 2, 4*NC), 256, 0, stream>>>(prm, xac, dlt, bc, szp, Pc, Qc, acc);
  k4_gemm_out<<<dim3(65, 8), 256, 0, stream>>>(acc, out_w, (float*)d_out);
}